// Round 13
// baseline (454.290 us; speedup 1.0000x reference)
//
#include <hip/hip_runtime.h>

#define DI __device__ __forceinline__

typedef short s16x8 __attribute__((ext_vector_type(8)));
typedef unsigned short u16;
typedef u16 u16x4 __attribute__((ext_vector_type(4)));
typedef u16 u16x8 __attribute__((ext_vector_type(8)));
typedef u16 u16x16 __attribute__((ext_vector_type(16)));
typedef float f32x4 __attribute__((ext_vector_type(4)));
typedef _Float16 f16;
typedef f16 f16x4 __attribute__((ext_vector_type(4)));

DI float bf2f(u16 v) { return __builtin_bit_cast(float, (unsigned)v << 16); }
DI u16 f2bf(float f) {
  unsigned u = __builtin_bit_cast(unsigned, f);
  return (u16)((u + 0x7fffu + ((u >> 16) & 1u)) >> 16);
}

// ---------------- weight prep: 8 casts + conv weight transpose, one launch ----------------
__global__ void k_prep(u16* __restrict__ wall,
    const float* __restrict__ s0, const float* __restrict__ s1,
    const float* __restrict__ s2, const float* __restrict__ s3,
    const float* __restrict__ s4, const float* __restrict__ s5,
    const float* __restrict__ s6, const float* __restrict__ s7,
    u16* __restrict__ Wtc, const float* __restrict__ pre_w) {
  int i = blockIdx.x * 256 + threadIdx.x;  // < 196608 + 589824
  if (i < 196608) {
    const float* src; int base;
    if (i < 32768) { src = s0; base = 0; }
    else if (i < 49152) { src = s1; base = 32768; }
    else if (i < 65536) { src = s2; base = 49152; }
    else if (i < 98304) { src = s3; base = 65536; }
    else if (i < 131072) { src = s4; base = 98304; }
    else if (i < 147456) { src = s5; base = 131072; }
    else if (i < 163840) { src = s6; base = 147456; }
    else { src = s7; base = 163840; }
    wall[i] = f2bf(src[i - base]);
  } else {
    int j = i - 196608;  // < 9*256*256
    int tap = j >> 16, rem = j & 65535;  // rem = o*256 + c
    Wtc[j] = f2bf(pre_w[(size_t)rem * 9 + tap]);
  }
}

// ---------------- pooled reductions + fp16 side-cast of x1..x4 ----------------
__global__ __launch_bounds__(256) void k_pool(
    const float* __restrict__ x0, const float* __restrict__ x1,
    const float* __restrict__ x2, const float* __restrict__ x3,
    const float* __restrict__ x4, float* __restrict__ pd, float* __restrict__ ps,
    f16* __restrict__ hx1, f16* __restrict__ hx2,
    f16* __restrict__ hx3, f16* __restrict__ hx4) {
  int c = blockIdx.x, b = blockIdx.y;
  size_t ebase = ((size_t)b * 256 + c) * 4096 + threadIdx.x * 4;
  float sd = 0.f, sm = 0.f;
#pragma unroll
  for (int it = 0; it < 4; ++it) {
    size_t off = ebase + it * 1024;
    f32x4 a0 = *(const f32x4*)(x0 + off);
    f32x4 a1 = *(const f32x4*)(x1 + off);
    f32x4 a2 = *(const f32x4*)(x2 + off);
    f32x4 a3 = *(const f32x4*)(x3 + off);
    f32x4 a4 = *(const f32x4*)(x4 + off);
    f16x4 h1, h2, h3, h4;
#pragma unroll
    for (int e = 0; e < 4; ++e) {
      float d = fabsf(a0[e] - a1[e]); d = fabsf(d - a2[e]); d = fabsf(d - a3[e]); d = fabsf(d - a4[e]);
      sd += d; sm += a0[e] + a1[e] + a2[e] + a3[e] + a4[e];
      h1[e] = (f16)a1[e]; h2[e] = (f16)a2[e]; h3[e] = (f16)a3[e]; h4[e] = (f16)a4[e];
    }
    *(f16x4*)(hx1 + off) = h1;
    *(f16x4*)(hx2 + off) = h2;
    *(f16x4*)(hx3 + off) = h3;
    *(f16x4*)(hx4 + off) = h4;
  }
  for (int o = 32; o; o >>= 1) { sd += __shfl_xor(sd, o); sm += __shfl_xor(sm, o); }
  __shared__ float rb[4][2];
  int wv = threadIdx.x >> 6, lane = threadIdx.x & 63;
  if (!lane) { rb[wv][0] = sd; rb[wv][1] = sm; }
  __syncthreads();
  if (!threadIdx.x) {
    float a = rb[0][0] + rb[1][0] + rb[2][0] + rb[3][0];
    float s2 = rb[0][1] + rb[1][1] + rb[2][1] + rb[3][1];
    pd[b * 256 + c] = a * (1.f / 4096.f);
    ps[b * 256 + c] = s2 * (1.f / 4096.f);
  }
}

// ---------------- SE layer 1 ----------------
__global__ __launch_bounds__(256) void k_se1(
    const float* __restrict__ pd, const float* __restrict__ ps,
    const float* __restrict__ sw1, const float* __restrict__ cw1,
    float* __restrict__ h1) {
  int b = blockIdx.y, z = blockIdx.z;
  int wv = threadIdx.x >> 6, lane = threadIdx.x & 63;
  int e = blockIdx.x * 4 + wv;
  const float* in = (z ? ps : pd) + b * 256;
  const float* w = (z ? cw1 : sw1) + (size_t)e * 256;
  float a = 0.f;
#pragma unroll
  for (int i = 0; i < 4; ++i) a += in[lane + 64 * i] * w[lane + 64 * i];
  for (int o = 32; o; o >>= 1) a += __shfl_xor(a, o);
  if (!lane) h1[((size_t)z * 16 + b) * 320 + e] = fmaxf(a, 0.f);
}

// ---------------- SE layer 2 ----------------
__global__ __launch_bounds__(256) void k_se2(
    const float* __restrict__ h1, const float* __restrict__ sw2,
    const float* __restrict__ cw2, float* __restrict__ h2) {
  int b = blockIdx.y, z = blockIdx.z;
  int wv = threadIdx.x >> 6, lane = threadIdx.x & 63;
  int e = blockIdx.x * 4 + wv;
  const float* in = h1 + ((size_t)z * 16 + b) * 320;
  const float* w = (z ? cw2 : sw2) + (size_t)e * 320;
  float a = 0.f;
#pragma unroll
  for (int i = 0; i < 5; ++i) a += in[lane + 64 * i] * w[lane + 64 * i];
  for (int o = 32; o; o >>= 1) a += __shfl_xor(a, o);
  if (!lane) h2[((size_t)z * 16 + b) * 1280 + e] = fmaxf(a, 0.f);
}

// ---------------- v3 weighted sum (se3 folded in) -> NHWC bf16 ----------------
__global__ __launch_bounds__(256) void k_v3(
    const float* __restrict__ x0, const f16* __restrict__ hx1,
    const f16* __restrict__ hx2, const f16* __restrict__ hx3,
    const f16* __restrict__ hx4, const float* __restrict__ h2b,
    u16* __restrict__ v3b) {
  int h = blockIdx.x, b = blockIdx.y;
  __shared__ float W[1280];
  __shared__ u16 T[256][68];
  int t = threadIdx.x;
  {  // se3: softmax-combine per channel t
    const float* Hs = h2b + (size_t)b * 1280;
    const float* Hc = h2b + (size_t)(16 + b) * 1280;
    float d0 = Hs[t], d1 = Hs[256 + t], d2 = Hs[512 + t], d3 = Hs[768 + t], d4 = Hs[1024 + t];
    float m = fmaxf(fmaxf(fmaxf(d0, d1), fmaxf(d2, d3)), d4);
    float e0 = expf(d0 - m), e1 = expf(d1 - m), e2 = expf(d2 - m), e3 = expf(d3 - m), e4 = expf(d4 - m);
    float inv = 1.f / (e0 + e1 + e2 + e3 + e4);
    float c0 = Hc[t], c1 = Hc[256 + t], c2 = Hc[512 + t], c3 = Hc[768 + t], c4 = Hc[1024 + t];
    float mc = fmaxf(fmaxf(fmaxf(c0, c1), fmaxf(c2, c3)), c4);
    float g0 = expf(c0 - mc), g1 = expf(c1 - mc), g2 = expf(c2 - mc), g3 = expf(c3 - mc), g4 = expf(c4 - mc);
    float ci = 1.f / (g0 + g1 + g2 + g3 + g4);
    W[t] = e0 * inv + g0 * ci + 1.f;
    W[256 + t] = e1 * inv + g1 * ci + 1.f;
    W[512 + t] = e2 * inv + g2 * ci + 1.f;
    W[768 + t] = e3 * inv + g3 * ci + 1.f;
    W[1024 + t] = e4 * inv + g4 * ci + 1.f;
  }
  __syncthreads();
  int csub = t >> 4, l16 = t & 15;
  size_t ebase = (size_t)b * 256 * 4096 + h * 64 + l16 * 4;  // + c*4096
#pragma unroll 4
  for (int ci = 0; ci < 16; ++ci) {
    int c = ci * 16 + csub;
    size_t a = ebase + (size_t)c * 4096;
    f32x4 v0 = *(const f32x4*)(x0 + a);
    f16x4 v1 = *(const f16x4*)(hx1 + a);
    f16x4 v2 = *(const f16x4*)(hx2 + a);
    f16x4 v3 = *(const f16x4*)(hx3 + a);
    f16x4 v4 = *(const f16x4*)(hx4 + a);
    float w0 = W[c], w1 = W[256 + c], w2 = W[512 + c], w3 = W[768 + c], w4 = W[1024 + c];
    u16x4 ov;
#pragma unroll
    for (int e = 0; e < 4; ++e)
      ov[e] = f2bf(v0[e] * w0 + (float)v1[e] * w1 + (float)v2[e] * w2 +
                   (float)v3[e] * w3 + (float)v4[e] * w4);
    *(u16x4*)(&T[c][l16 * 4]) = ov;
  }
  __syncthreads();
  int w = t >> 2, oct = t & 3;
  size_t obase = ((size_t)b * 4096 + h * 64 + w) * 256;
  for (int pass = 0; pass < 8; ++pass) {
    int c0 = oct * 8 + pass * 32;
    u16x8 ov;
#pragma unroll
    for (int jj = 0; jj < 8; ++jj) ov[jj] = T[c0 + jj][w];
    *(u16x8*)(v3b + obase + c0) = ov;
  }
}

// ---------------- 3x3 conv: A (no w-halo) + B double-buffer, 2-deep B reg prefetch ----------------
__global__ __launch_bounds__(256) void k_conv(
    const u16* __restrict__ v3b, const u16* __restrict__ Wt,
    const float* __restrict__ bias, u16* __restrict__ pre) {
  int o = blockIdx.x;
  int wg = (o & 7) * 128 + (o >> 3);  // bijective XCD swizzle (1024 % 8 == 0)
  int oh = wg & 1, hp = (wg >> 1) & 31, b = wg >> 6;
  __shared__ __align__(16) u16 Ain[4 * 64 * 40];
  __shared__ __align__(16) u16 Bls[2][128 * 40];
  int t = threadIdx.x, wv = t >> 6, lane = t & 63;
  int wm = (wv >> 1) * 64, wn = (wv & 1) * 64, fr = lane & 15, ko = lane >> 4;

  auto loadA = [&](int cc, int s) -> u16x16 {
    int r = s >> 7, rest = s & 127, w = rest >> 1, half = rest & 1;
    int hs = hp * 2 - 1 + r;
    u16x16 v = {};
    if ((unsigned)hs < 64u)
      v = *(const u16x16*)(v3b + (((size_t)b * 64 + hs) * 64 + w) * 256 + cc * 32 + half * 16);
    return v;
  };
  auto storeA = [&](int s, u16x16 v) {
    int r = s >> 7, rest = s & 127, w = rest >> 1, half = rest & 1;
    *(u16x16*)(Ain + (r * 64 + w) * 40 + half * 16) = v;
  };
  auto loadB = [&](int tap, int cc) -> u16x16 {
    int n = t >> 1, half = t & 1;
    return *(const u16x16*)(Wt + ((size_t)tap * 256 + oh * 128 + n) * 256 + cc * 32 + half * 16);
  };
  auto storeB = [&](int bsel, u16x16 v) {
    int n = t >> 1, half = t & 1;
    *(u16x16*)(Bls[bsel] + n * 40 + half * 16) = v;
  };

  u16x16 pA0 = loadA(0, t), pA1 = loadA(0, t + 256);
  u16x16 rB0 = loadB(0, 0);
  storeA(t, pA0); storeA(t + 256, pA1); storeB(0, rB0);
  rB0 = loadB(1, 0);             // B(1)
  u16x16 rB1 = loadB(2, 0);      // B(2)
  __syncthreads();

  f32x4 acc[4][4] = {};
  int buf = 0;
  for (int cc = 0; cc < 8; ++cc) {
#pragma unroll
    for (int tap = 0; tap < 9; ++tap) {
      const int dh = tap / 3 - 1, dw = tap % 3 - 1;
      s16x8 af[4], bfr[4];
#pragma unroll
      for (int i = 0; i < 4; ++i) {
        int m = wm + i * 16 + fr, r = m >> 6, wq = m & 63;
        int wqd = wq + dw;
        s16x8 v = {};
        if ((unsigned)wqd < 64u)
          v = *(const s16x8*)(Ain + ((r + dh + 1) * 64 + wqd) * 40 + ko * 8);
        af[i] = v;
      }
#pragma unroll
      for (int j = 0; j < 4; ++j)
        bfr[j] = *(const s16x8*)(Bls[buf] + (wn + j * 16 + fr) * 40 + ko * 8);
#pragma unroll
      for (int i = 0; i < 4; ++i)
#pragma unroll
        for (int j = 0; j < 4; ++j)
          acc[i][j] = __builtin_amdgcn_mfma_f32_16x16x32_bf16(af[i], bfr[j], acc[i][j], 0, 0, 0);
      const int u = cc * 9 + tap;
      if (u < 71) {
        if (tap == 8) {
          __syncthreads();  // Ain readers done before rewrite
          storeA(t, pA0); storeA(t + 256, pA1);
        }
        storeB(buf ^ 1, rB0);  // B(u+1): readers of buf^1 finished before last barrier
        rB0 = rB1;
        if (u + 3 <= 71) {
          const int un = u + 3;
          rB1 = loadB(un % 9, un / 9);
        }
        if (tap == 7 && cc < 7) { pA0 = loadA(cc + 1, t); pA1 = loadA(cc + 1, t + 256); }
        __syncthreads();
        buf ^= 1;
      }
    }
  }
#pragma unroll
  for (int i = 0; i < 4; ++i) {
    int m0 = wm + i * 16 + ko * 4;
#pragma unroll
    for (int j = 0; j < 4; ++j) {
      int och = oh * 128 + wn + j * 16 + fr;
      float bv = bias[och];
#pragma unroll
      for (int r = 0; r < 4; ++r) {
        float v = fmaxf(acc[i][j][r] + bv, 0.f);
        pre[((size_t)b * 4096 + hp * 128 + m0 + r) * 256 + och] = f2bf(v);
      }
    }
  }
}

// ---------------- fused red -> v,k (norm) + local gram partial per 128-token tile ----------------
__global__ __launch_bounds__(256) void k_qkv(
    const u16* __restrict__ in,    // [B*4096][256]
    const u16* __restrict__ redW,  // [128][256]
    const u16* __restrict__ wkW,   // [128][128]
    const u16* __restrict__ wvW,   // [128][128]
    const float* __restrict__ kb, const float* __restrict__ vb,
    u16* __restrict__ vout,        // [B*4096][128]
    float* __restrict__ gp) {      // [B*32][128][128]
  int nt = blockIdx.x, b = blockIdx.y;
  const u16* Ab = in + ((size_t)b * 4096 + nt * 128) * 256;
  __shared__ __align__(16) u16 Ald[128 * 40];
  __shared__ __align__(16) u16 Bld[128 * 40];
  __shared__ __align__(16) u16 T[128 * 136];
  __shared__ float SS[2][128];
  int t = threadIdx.x, wv = t >> 6, lane = t & 63;
  int wm = (wv >> 1) * 64, wn = (wv & 1) * 64, fr = lane & 15, ko = lane >> 4;
  f32x4 acc[4][4] = {};
  for (int kc = 0; kc < 256; kc += 32) {
    for (int s = t; s < 512; s += 256) {
      int r = s >> 2, ks = s & 3;
      *(u16x8*)(Ald + r * 40 + ks * 8) = *(const u16x8*)(Ab + (size_t)r * 256 + kc + ks * 8);
    }
    for (int s = t; s < 512; s += 256) {
      int r = s >> 2, ks = s & 3;
      *(u16x8*)(Bld + r * 40 + ks * 8) = *(const u16x8*)(redW + (size_t)r * 256 + kc + ks * 8);
    }
    __syncthreads();
    s16x8 af[4], bf[4];
#pragma unroll
    for (int i = 0; i < 4; ++i) af[i] = *(const s16x8*)(Ald + (wm + i * 16 + fr) * 40 + ko * 8);
#pragma unroll
    for (int j = 0; j < 4; ++j) bf[j] = *(const s16x8*)(Bld + (wn + j * 16 + fr) * 40 + ko * 8);
#pragma unroll
    for (int i = 0; i < 4; ++i)
#pragma unroll
      for (int j = 0; j < 4; ++j)
        acc[i][j] = __builtin_amdgcn_mfma_f32_16x16x32_bf16(af[i], bf[j], acc[i][j], 0, 0, 0);
    __syncthreads();
  }
#pragma unroll
  for (int i = 0; i < 4; ++i)
#pragma unroll
    for (int j = 0; j < 4; ++j)
#pragma unroll
      for (int r = 0; r < 4; ++r)
        T[(wm + i * 16 + ko * 4 + r) * 136 + wn + j * 16 + fr] = f2bf(acc[i][j][r]);

  for (int z = 0; z < 2; ++z) {
    const u16* W = z ? wkW : wvW;
    const float* bias = z ? kb : vb;
    f32x4 a2[4][4] = {};
#pragma unroll
    for (int h = 0; h < 2; ++h) {
      __syncthreads();
      for (int s = t; s < 512; s += 256) {
        int r = s >> 2, ks = s & 3;
        *(u16x8*)(Ald + r * 40 + ks * 8) = *(const u16x8*)(W + (size_t)r * 128 + h * 64 + ks * 8);
      }
      for (int s = t; s < 512; s += 256) {
        int r = s >> 2, ks = s & 3;
        *(u16x8*)(Bld + r * 40 + ks * 8) = *(const u16x8*)(W + (size_t)r * 128 + h * 64 + 32 + ks * 8);
      }
      __syncthreads();
#pragma unroll
      for (int kk = 0; kk < 2; ++kk) {
        const u16* Bsrc = kk ? Bld : Ald;
        s16x8 af[4], bf[4];
#pragma unroll
        for (int i = 0; i < 4; ++i)
          af[i] = *(const s16x8*)(T + (size_t)(wm + i * 16 + fr) * 136 + h * 64 + kk * 32 + ko * 8);
#pragma unroll
        for (int j = 0; j < 4; ++j)
          bf[j] = *(const s16x8*)(Bsrc + (wn + j * 16 + fr) * 40 + ko * 8);
#pragma unroll
        for (int i = 0; i < 4; ++i)
#pragma unroll
          for (int j = 0; j < 4; ++j)
            a2[i][j] = __builtin_amdgcn_mfma_f32_16x16x32_bf16(af[i], bf[j], a2[i][j], 0, 0, 0);
      }
    }
    float bj[4];
#pragma unroll
    for (int j = 0; j < 4; ++j) bj[j] = bias[wn + j * 16 + fr];
    float pss[4][4];
#pragma unroll
    for (int i = 0; i < 4; ++i)
#pragma unroll
      for (int r = 0; r < 4; ++r) pss[i][r] = 0.f;
#pragma unroll
    for (int i = 0; i < 4; ++i)
#pragma unroll
      for (int j = 0; j < 4; ++j)
#pragma unroll
        for (int r = 0; r < 4; ++r) {
          float v = a2[i][j][r] + bj[j];
          a2[i][j][r] = v;
          pss[i][r] += v * v;
        }
#pragma unroll
    for (int m = 1; m < 16; m <<= 1)
#pragma unroll
      for (int i = 0; i < 4; ++i)
#pragma unroll
        for (int r = 0; r < 4; ++r) pss[i][r] += __shfl_xor(pss[i][r], m);
    if (fr == 0)
#pragma unroll
      for (int i = 0; i < 4; ++i)
#pragma unroll
        for (int r = 0; r < 4; ++r) SS[wv & 1][wm + i * 16 + ko * 4 + r] = pss[i][r];
    __syncthreads();
    float sc[4][4];
#pragma unroll
    for (int i = 0; i < 4; ++i)
#pragma unroll
      for (int r = 0; r < 4; ++r) {
        int tok = wm + i * 16 + ko * 4 + r;
        float s2 = SS[0][tok] + SS[1][tok];
        sc[i][r] = 1.f / fmaxf(sqrtf(s2), 1e-12f);
      }
#pragma unroll
    for (int i = 0; i < 4; ++i)
#pragma unroll
      for (int j = 0; j < 4; ++j)
#pragma unroll
        for (int r = 0; r < 4; ++r) a2[i][j][r] *= sc[i][r];
    if (z == 0) {
      size_t tokbase = (size_t)b * 4096 + nt * 128;
#pragma unroll
      for (int i = 0; i < 4; ++i)
#pragma unroll
        for (int j = 0; j < 4; ++j) {
          u16* dst = vout + (tokbase + wm + i * 16 + ko * 4) * 128 + wn + j * 16 + fr;
#pragma unroll
          for (int r = 0; r < 4; ++r) dst[(size_t)r * 128] = f2bf(a2[i][j][r]);
        }
    } else {
#pragma unroll
      for (int i = 0; i < 4; ++i)
#pragma unroll
        for (int j = 0; j < 4; ++j)
#pragma unroll
          for (int r = 0; r < 4; ++r)
            T[(size_t)(wn + j * 16 + fr) * 136 + wm + i * 16 + ko * 4 + r] = f2bf(a2[i][j][r]);
      __syncthreads();
      f32x4 g3[4][4] = {};
      for (int kc = 0; kc < 128; kc += 32) {
        s16x8 af[4], bf[4];
#pragma unroll
        for (int i = 0; i < 4; ++i)
          af[i] = *(const s16x8*)(T + (size_t)(wm + i * 16 + fr) * 136 + kc + ko * 8);
#pragma unroll
        for (int j = 0; j < 4; ++j)
          bf[j] = *(const s16x8*)(T + (size_t)(wn + j * 16 + fr) * 136 + kc + ko * 8);
#pragma unroll
        for (int i = 0; i < 4; ++i)
#pragma unroll
          for (int j = 0; j < 4; ++j)
            g3[i][j] = __builtin_amdgcn_mfma_f32_16x16x32_bf16(af[i], bf[j], g3[i][j], 0, 0, 0);
      }
      float* dst = gp + ((size_t)(b * 32 + nt)) * 16384;
#pragma unroll
      for (int i = 0; i < 4; ++i) {
        int m0 = wm + i * 16 + ko * 4;
#pragma unroll
        for (int j = 0; j < 4; ++j) {
          int nc = wn + j * 16 + fr;
#pragma unroll
          for (int r = 0; r < 4; ++r) dst[(size_t)(m0 + r) * 128 + nc] = g3[i][j][r];
        }
      }
    }
  }
}

// ---------------- fused PV + rise per 128-token tile ----------------
template <int MODE>
__global__ __launch_bounds__(256) void k_pvrise(
    const u16* __restrict__ vbuf,   // [B*4096][128]
    const u16* __restrict__ attnb,  // [B][128][128]
    const u16* __restrict__ riseW,  // [256][128]
    const float* __restrict__ bias,
    const u16* __restrict__ add0, const u16* __restrict__ add1,
    u16* __restrict__ out0, u16* __restrict__ out1, float* __restrict__ outf) {
  int nt = blockIdx.x, b = blockIdx.y;
  const u16* Ab = vbuf + ((size_t)b * 4096 + nt * 128) * 128;
  const u16* Bb = attnb + (size_t)b * 128 * 128;
  __shared__ __align__(16) u16 Ald[128 * 40];
  __shared__ __align__(16) u16 Bld[128 * 40];
  __shared__ __align__(16) u16 T[128 * 136];
  int t = threadIdx.x, wv = t >> 6, lane = t & 63;
  int wm = (wv >> 1) * 64, wn = (wv & 1) * 64, fr = lane & 15, ko = lane >> 4;
  f32x4 acc[4][4] = {};
  for (int kc = 0; kc < 128; kc += 32) {
    for (int s = t; s < 512; s += 256) {
      int r = s >> 2, ks = s & 3;
      *(u16x8*)(Ald + r * 40 + ks * 8) = *(const u16x8*)(Ab + (size_t)r * 128 + kc + ks * 8);
    }
    for (int s = t; s < 512; s += 256) {
      int r = s >> 2, ks = s & 3;
      *(u16x8*)(Bld + r * 40 + ks * 8) = *(const u16x8*)(Bb + (size_t)r * 128 + kc + ks * 8);
    }
    __syncthreads();
    s16x8 af[4], bf[4];
#pragma unroll
    for (int i = 0; i < 4; ++i) af[i] = *(const s16x8*)(Ald + (wm + i * 16 + fr) * 40 + ko * 8);
#pragma unroll
    for (int j = 0; j < 4; ++j) bf[j] = *(const s16x8*)(Bld + (wn + j * 16 + fr) * 40 + ko * 8);
#pragma unroll
    for (int i = 0; i < 4; ++i)
#pragma unroll
      for (int j = 0; j < 4; ++j)
        acc[i][j] = __builtin_amdgcn_mfma_f32_16x16x32_bf16(af[i], bf[j], acc[i][j], 0, 0, 0);
    __syncthreads();
  }
#pragma unroll
  for (int i = 0; i < 4; ++i)
#pragma unroll
    for (int j = 0; j < 4; ++j)
#pragma unroll
      for (int r = 0; r < 4; ++r)
        T[(wm + i * 16 + ko * 4 + r) * 136 + wn + j * 16 + fr] = f2bf(acc[i][j][r]);

  size_t tokbase = (size_t)b * 4096 + nt * 128;
  for (int z = 0; z < 2; ++z) {
    const u16* W = riseW + (size_t)z * 128 * 128;
    f32x4 a2[4][4] = {};
#pragma unroll
    for (int h = 0; h < 2; ++h) {
      __syncthreads();
      for (int s = t; s < 512; s += 256) {
        int r = s >> 2, ks = s & 3;
        *(u16x8*)(Ald + r * 40 + ks * 8) = *(const u16x8*)(W + (size_t)r * 128 + h * 64 + ks * 8);
      }
      for (int s = t; s < 512; s += 256) {
        int r = s >> 2, ks = s & 3;
        *(u16x8*)(Bld + r * 40 + ks * 8) = *(const u16x8*)(W + (size_t)r * 128 + h * 64 + 32 + ks * 8);
      }
      __syncthreads();
#pragma unroll
      for (int kk = 0; kk < 2; ++kk) {
        const u16* Bsrc = kk ? Bld : Ald;
        s16x8 af[4], bf[4];
#pragma unroll
        for (int i = 0; i < 4; ++i)
          af[i] = *(const s16x8*)(T + (size_t)(wm + i * 16 + fr) * 136 + h * 64 + kk * 32 + ko * 8);
#pragma unroll
        for (int j = 0; j < 4; ++j)
          bf[j] = *(const s16x8*)(Bsrc + (wn + j * 16 + fr) * 40 + ko * 8);
#pragma unroll
        for (int i = 0; i < 4; ++i)
#pragma unroll
          for (int j = 0; j < 4; ++j)
            a2[i][j] = __builtin_amdgcn_mfma_f32_16x16x32_bf16(af[i], bf[j], a2[i][j], 0, 0, 0);
      }
    }
#pragma unroll
    for (int i = 0; i < 4; ++i) {
      int m0 = wm + i * 16 + ko * 4;
#pragma unroll
      for (int j = 0; j < 4; ++j) {
        int o = z * 128 + wn + j * 16 + fr;
        float bv = bias[o];
        size_t idx = (tokbase + m0) * 256 + o;
        if constexpr (MODE == 3) {
#pragma unroll
          for (int r = 0; r < 4; ++r) {
            float f1v = a2[i][j][r] + bv;
            out0[idx + (size_t)r * 256] = f2bf(f1v);
            out1[idx + (size_t)r * 256] = f2bf(f1v + bf2f(add0[idx + (size_t)r * 256]));
          }
        } else {
          f32x4 vv;
#pragma unroll
          for (int r = 0; r < 4; ++r)
            vv[r] = a2[i][j][r] + bv + bf2f(add0[idx + (size_t)r * 256]) +
                    bf2f(add1[idx + (size_t)r * 256]);
          *(f32x4*)(outf + ((size_t)b * 256 + o) * 4096 + nt * 128 + m0) = vv;
        }
      }
    }
  }
}

// ---------------- softmax over j of 30*G (32 partials) ----------------
__global__ void k_soft(const float* __restrict__ gp, u16* __restrict__ attn) {
  int i = blockIdx.x, b = blockIdx.y, l = threadIdx.x;
  float s0 = 0.f, s1 = 0.f;
  for (int ks = 0; ks < 32; ++ks) {
    const float* row = gp + ((size_t)(b * 32 + ks)) * 16384 + (size_t)i * 128;
    s0 += row[l]; s1 += row[l + 64];
  }
  s0 *= 30.f; s1 *= 30.f;
  float m = fmaxf(s0, s1);
  for (int o = 32; o; o >>= 1) m = fmaxf(m, __shfl_xor(m, o));
  float e0 = expf(s0 - m), e1 = expf(s1 - m);
  float s = e0 + e1;
  for (int o = 32; o; o >>= 1) s += __shfl_xor(s, o);
  float inv = 1.f / s;
  u16* dst = attn + ((size_t)b * 128 + i) * 128;
  dst[l] = f2bf(e0 * inv);
  dst[l + 64] = f2bf(e1 * inv);
}

extern "C" void kernel_launch(void* const* d_in, const int* in_sizes, int n_in,
                              void* d_out, int out_size, void* d_ws, size_t ws_size,
                              hipStream_t stream) {
  (void)in_sizes; (void)n_in; (void)out_size; (void)ws_size;
  const float* x0 = (const float*)d_in[0];
  const float* x1 = (const float*)d_in[1];
  const float* x2 = (const float*)d_in[2];
  const float* x3 = (const float*)d_in[3];
  const float* x4 = (const float*)d_in[4];
  const float* spec_w1 = (const float*)d_in[5];
  const float* spec_w2 = (const float*)d_in[6];
  const float* comm_w1 = (const float*)d_in[7];
  const float* comm_w2 = (const float*)d_in[8];
  const float* pre_w = (const float*)d_in[9];
  const float* pre_bias = (const float*)d_in[10];
  const float* wk1_w = (const float*)d_in[11];
  const float* wk1_b = (const float*)d_in[12];
  const float* wv1_w = (const float*)d_in[13];
  const float* wv1_b = (const float*)d_in[14];
  const float* red1_w = (const float*)d_in[15];
  const float* rise1_w = (const float*)d_in[16];
  const float* rise1_b = (const float*)d_in[17];
  const float* wk2_w = (const float*)d_in[18];
  const float* wk2_b = (const float*)d_in[19];
  const float* wv2_w = (const float*)d_in[20];
  const float* wv2_b = (const float*)d_in[21];
  const float* red2_w = (const float*)d_in[22];
  const float* rise2_w = (const float*)d_in[23];
  const float* rise2_b = (const float*)d_in[24];
  float* out = (float*)d_out;

  char* wsp = (char*)d_ws;
  size_t off = 0;
  auto alloc = [&](size_t bytes) -> void* {
    off = (off + 255) & ~(size_t)255;
    void* p = wsp + off;
    off += bytes;
    return p;
  };
  float* pd = (float*)alloc(16 * 256 * 4);
  float* ps = (float*)alloc(16 * 256 * 4);
  float* h1b = (float*)alloc(2 * 16 * 320 * 4);
  float* h2b = (float*)alloc(2 * 16 * 1280 * 4);
  u16* v3b = (u16*)alloc((size_t)16 * 4096 * 256 * 2);
  u16* Wtc = (u16*)alloc((size_t)9 * 256 * 256 * 2);
  u16* wall = (u16*)alloc((size_t)196608 * 2);  // 8 small weights, contiguous
  u16* red1b = wall;
  u16* wk1b = wall + 32768;
  u16* wv1b = wall + 49152;
  u16* rise1b = wall + 65536;
  u16* red2b = wall + 98304;
  u16* wk2b = wall + 131072;
  u16* wv2b = wall + 147456;
  u16* rise2b = wall + 163840;
  u16* pre = (u16*)alloc((size_t)16 * 4096 * 256 * 2);   // reused as in2 = f1+v3
  float* gpart = (float*)alloc((size_t)16 * 32 * 128 * 128 * 4);  // 32 MB
  u16* vbuf = (u16*)alloc((size_t)16 * 4096 * 128 * 2);
  u16* attn = (u16*)alloc((size_t)16 * 128 * 128 * 2);
  u16* spacer = (u16*)alloc((size_t)16 * 4096 * 128 * 2);  // keeps hx arena span
  u16* f1b = (u16*)alloc((size_t)16 * 4096 * 256 * 2);
  (void)spacer;
  u16* in2b = pre;
  // fp16 x1..x4 arena ALIASES the post-v3 buffers (pre..f1b span >= 134.2 MB).
  // Safe: written by k_pool, read by k_v3, both BEFORE k_conv first writes `pre`.
  f16* hx = (f16*)pre;
  const size_t HXN = (size_t)16 * 256 * 4096;  // elems per tensor
  f16* hx1 = hx;
  f16* hx2 = hx + HXN;
  f16* hx3 = hx + 2 * HXN;
  f16* hx4 = hx + 3 * HXN;

  // weight prep (one launch)
  k_prep<<<dim3(3072), 256, 0, stream>>>(wall, red1_w, wk1_w, wv1_w, rise1_w,
                                         red2_w, wk2_w, wv2_w, rise2_w, Wtc, pre_w);

  k_pool<<<dim3(256, 16), 256, 0, stream>>>(x0, x1, x2, x3, x4, pd, ps, hx1, hx2, hx3, hx4);
  k_se1<<<dim3(80, 16, 2), 256, 0, stream>>>(pd, ps, spec_w1, comm_w1, h1b);
  k_se2<<<dim3(320, 16, 2), 256, 0, stream>>>(h1b, spec_w2, comm_w2, h2b);
  k_v3<<<dim3(64, 16), 256, 0, stream>>>(x0, hx1, hx2, hx3, hx4, h2b, v3b);
  k_conv<<<dim3(1024), 256, 0, stream>>>(v3b, Wtc, pre_bias, pre);

  // ---- tdec 1 ----
  k_qkv<<<dim3(32, 16), 256, 0, stream>>>(pre, red1b, wk1b, wv1b, wk1_b, wv1_b, vbuf, gpart);
  k_soft<<<dim3(128, 16), 64, 0, stream>>>(gpart, attn);
  k_pvrise<3><<<dim3(32, 16), 256, 0, stream>>>(vbuf, attn, rise1b, rise1_b,
      v3b, nullptr, f1b, in2b, nullptr);

  // ---- tdec 2 (input in2b aliases pre) ----
  k_qkv<<<dim3(32, 16), 256, 0, stream>>>(in2b, red2b, wk2b, wv2b, wk2_b, wv2_b, vbuf, gpart);
  k_soft<<<dim3(128, 16), 64, 0, stream>>>(gpart, attn);
  k_pvrise<4><<<dim3(32, 16), 256, 0, stream>>>(vbuf, attn, rise2b, rise2_b,
      f1b, v3b, nullptr, nullptr, out);
}

// Round 14
// 431.551 us; speedup vs baseline: 1.0527x; 1.0527x over previous
//
#include <hip/hip_runtime.h>

#define DI __device__ __forceinline__

typedef short s16x8 __attribute__((ext_vector_type(8)));
typedef unsigned short u16;
typedef u16 u16x4 __attribute__((ext_vector_type(4)));
typedef u16 u16x8 __attribute__((ext_vector_type(8)));
typedef u16 u16x16 __attribute__((ext_vector_type(16)));
typedef float f32x4 __attribute__((ext_vector_type(4)));
typedef _Float16 f16;
typedef f16 f16x4 __attribute__((ext_vector_type(4)));

DI float bf2f(u16 v) { return __builtin_bit_cast(float, (unsigned)v << 16); }
DI u16 f2bf(float f) {
  unsigned u = __builtin_bit_cast(unsigned, f);
  return (u16)((u + 0x7fffu + ((u >> 16) & 1u)) >> 16);
}

// ---------------- weight prep: 8 casts + conv weight transpose, one launch ----------------
__global__ void k_prep(u16* __restrict__ wall,
    const float* __restrict__ s0, const float* __restrict__ s1,
    const float* __restrict__ s2, const float* __restrict__ s3,
    const float* __restrict__ s4, const float* __restrict__ s5,
    const float* __restrict__ s6, const float* __restrict__ s7,
    u16* __restrict__ Wtc, const float* __restrict__ pre_w) {
  int i = blockIdx.x * 256 + threadIdx.x;  // < 196608 + 589824
  if (i < 196608) {
    const float* src; int base;
    if (i < 32768) { src = s0; base = 0; }
    else if (i < 49152) { src = s1; base = 32768; }
    else if (i < 65536) { src = s2; base = 49152; }
    else if (i < 98304) { src = s3; base = 65536; }
    else if (i < 131072) { src = s4; base = 98304; }
    else if (i < 147456) { src = s5; base = 131072; }
    else if (i < 163840) { src = s6; base = 147456; }
    else { src = s7; base = 163840; }
    wall[i] = f2bf(src[i - base]);
  } else {
    int j = i - 196608;  // < 9*256*256
    int tap = j >> 16, rem = j & 65535;  // rem = o*256 + c
    Wtc[j] = f2bf(pre_w[(size_t)rem * 9 + tap]);
  }
}

// ---------------- pooled reductions + fp16 side-cast of x1..x4 ----------------
__global__ __launch_bounds__(256) void k_pool(
    const float* __restrict__ x0, const float* __restrict__ x1,
    const float* __restrict__ x2, const float* __restrict__ x3,
    const float* __restrict__ x4, float* __restrict__ pd, float* __restrict__ ps,
    f16* __restrict__ hx1, f16* __restrict__ hx2,
    f16* __restrict__ hx3, f16* __restrict__ hx4) {
  int c = blockIdx.x, b = blockIdx.y;
  size_t ebase = ((size_t)b * 256 + c) * 4096 + threadIdx.x * 4;
  float sd = 0.f, sm = 0.f;
#pragma unroll
  for (int it = 0; it < 4; ++it) {
    size_t off = ebase + it * 1024;
    f32x4 a0 = *(const f32x4*)(x0 + off);
    f32x4 a1 = *(const f32x4*)(x1 + off);
    f32x4 a2 = *(const f32x4*)(x2 + off);
    f32x4 a3 = *(const f32x4*)(x3 + off);
    f32x4 a4 = *(const f32x4*)(x4 + off);
    f16x4 h1, h2, h3, h4;
#pragma unroll
    for (int e = 0; e < 4; ++e) {
      float d = fabsf(a0[e] - a1[e]); d = fabsf(d - a2[e]); d = fabsf(d - a3[e]); d = fabsf(d - a4[e]);
      sd += d; sm += a0[e] + a1[e] + a2[e] + a3[e] + a4[e];
      h1[e] = (f16)a1[e]; h2[e] = (f16)a2[e]; h3[e] = (f16)a3[e]; h4[e] = (f16)a4[e];
    }
    *(f16x4*)(hx1 + off) = h1;
    *(f16x4*)(hx2 + off) = h2;
    *(f16x4*)(hx3 + off) = h3;
    *(f16x4*)(hx4 + off) = h4;
  }
  for (int o = 32; o; o >>= 1) { sd += __shfl_xor(sd, o); sm += __shfl_xor(sm, o); }
  __shared__ float rb[4][2];
  int wv = threadIdx.x >> 6, lane = threadIdx.x & 63;
  if (!lane) { rb[wv][0] = sd; rb[wv][1] = sm; }
  __syncthreads();
  if (!threadIdx.x) {
    float a = rb[0][0] + rb[1][0] + rb[2][0] + rb[3][0];
    float s2 = rb[0][1] + rb[1][1] + rb[2][1] + rb[3][1];
    pd[b * 256 + c] = a * (1.f / 4096.f);
    ps[b * 256 + c] = s2 * (1.f / 4096.f);
  }
}

// ---------------- SE layer 1 ----------------
__global__ __launch_bounds__(256) void k_se1(
    const float* __restrict__ pd, const float* __restrict__ ps,
    const float* __restrict__ sw1, const float* __restrict__ cw1,
    float* __restrict__ h1) {
  int b = blockIdx.y, z = blockIdx.z;
  int wv = threadIdx.x >> 6, lane = threadIdx.x & 63;
  int e = blockIdx.x * 4 + wv;
  const float* in = (z ? ps : pd) + b * 256;
  const float* w = (z ? cw1 : sw1) + (size_t)e * 256;
  float a = 0.f;
#pragma unroll
  for (int i = 0; i < 4; ++i) a += in[lane + 64 * i] * w[lane + 64 * i];
  for (int o = 32; o; o >>= 1) a += __shfl_xor(a, o);
  if (!lane) h1[((size_t)z * 16 + b) * 320 + e] = fmaxf(a, 0.f);
}

// ---------------- SE layer 2 ----------------
__global__ __launch_bounds__(256) void k_se2(
    const float* __restrict__ h1, const float* __restrict__ sw2,
    const float* __restrict__ cw2, float* __restrict__ h2) {
  int b = blockIdx.y, z = blockIdx.z;
  int wv = threadIdx.x >> 6, lane = threadIdx.x & 63;
  int e = blockIdx.x * 4 + wv;
  const float* in = h1 + ((size_t)z * 16 + b) * 320;
  const float* w = (z ? cw2 : sw2) + (size_t)e * 320;
  float a = 0.f;
#pragma unroll
  for (int i = 0; i < 5; ++i) a += in[lane + 64 * i] * w[lane + 64 * i];
  for (int o = 32; o; o >>= 1) a += __shfl_xor(a, o);
  if (!lane) h2[((size_t)z * 16 + b) * 1280 + e] = fmaxf(a, 0.f);
}

// ---------------- v3 weighted sum (se3 folded in) -> NHWC bf16 ----------------
__global__ __launch_bounds__(256) void k_v3(
    const float* __restrict__ x0, const f16* __restrict__ hx1,
    const f16* __restrict__ hx2, const f16* __restrict__ hx3,
    const f16* __restrict__ hx4, const float* __restrict__ h2b,
    u16* __restrict__ v3b) {
  int h = blockIdx.x, b = blockIdx.y;
  __shared__ float W[1280];
  __shared__ u16 T[256][68];
  int t = threadIdx.x;
  {  // se3: softmax-combine per channel t
    const float* Hs = h2b + (size_t)b * 1280;
    const float* Hc = h2b + (size_t)(16 + b) * 1280;
    float d0 = Hs[t], d1 = Hs[256 + t], d2 = Hs[512 + t], d3 = Hs[768 + t], d4 = Hs[1024 + t];
    float m = fmaxf(fmaxf(fmaxf(d0, d1), fmaxf(d2, d3)), d4);
    float e0 = expf(d0 - m), e1 = expf(d1 - m), e2 = expf(d2 - m), e3 = expf(d3 - m), e4 = expf(d4 - m);
    float inv = 1.f / (e0 + e1 + e2 + e3 + e4);
    float c0 = Hc[t], c1 = Hc[256 + t], c2 = Hc[512 + t], c3 = Hc[768 + t], c4 = Hc[1024 + t];
    float mc = fmaxf(fmaxf(fmaxf(c0, c1), fmaxf(c2, c3)), c4);
    float g0 = expf(c0 - mc), g1 = expf(c1 - mc), g2 = expf(c2 - mc), g3 = expf(c3 - mc), g4 = expf(c4 - mc);
    float ci = 1.f / (g0 + g1 + g2 + g3 + g4);
    W[t] = e0 * inv + g0 * ci + 1.f;
    W[256 + t] = e1 * inv + g1 * ci + 1.f;
    W[512 + t] = e2 * inv + g2 * ci + 1.f;
    W[768 + t] = e3 * inv + g3 * ci + 1.f;
    W[1024 + t] = e4 * inv + g4 * ci + 1.f;
  }
  __syncthreads();
  int csub = t >> 4, l16 = t & 15;
  size_t ebase = (size_t)b * 256 * 4096 + h * 64 + l16 * 4;  // + c*4096
#pragma unroll 4
  for (int ci = 0; ci < 16; ++ci) {
    int c = ci * 16 + csub;
    size_t a = ebase + (size_t)c * 4096;
    f32x4 v0 = *(const f32x4*)(x0 + a);
    f16x4 v1 = *(const f16x4*)(hx1 + a);
    f16x4 v2 = *(const f16x4*)(hx2 + a);
    f16x4 v3 = *(const f16x4*)(hx3 + a);
    f16x4 v4 = *(const f16x4*)(hx4 + a);
    float w0 = W[c], w1 = W[256 + c], w2 = W[512 + c], w3 = W[768 + c], w4 = W[1024 + c];
    u16x4 ov;
#pragma unroll
    for (int e = 0; e < 4; ++e)
      ov[e] = f2bf(v0[e] * w0 + (float)v1[e] * w1 + (float)v2[e] * w2 +
                   (float)v3[e] * w3 + (float)v4[e] * w4);
    *(u16x4*)(&T[c][l16 * 4]) = ov;
  }
  __syncthreads();
  int w = t >> 2, oct = t & 3;
  size_t obase = ((size_t)b * 4096 + h * 64 + w) * 256;
  for (int pass = 0; pass < 8; ++pass) {
    int c0 = oct * 8 + pass * 32;
    u16x8 ov;
#pragma unroll
    for (int jj = 0; jj < 8; ++jj) ov[jj] = T[c0 + jj][w];
    *(u16x8*)(v3b + obase + c0) = ov;
  }
}

// ---------------- 3x3 conv: A (no w-halo) + B double-buffer, 1-deep reg prefetch ----------------
// (Round-12 proven version: VGPR <= 128, LDS 40960 -> 4 blocks/CU)
__global__ __launch_bounds__(256) void k_conv(
    const u16* __restrict__ v3b, const u16* __restrict__ Wt,
    const float* __restrict__ bias, u16* __restrict__ pre) {
  int o = blockIdx.x;
  int wg = (o & 7) * 128 + (o >> 3);  // bijective XCD swizzle (1024 % 8 == 0)
  int oh = wg & 1, hp = (wg >> 1) & 31, b = wg >> 6;
  __shared__ __align__(16) u16 Ain[4 * 64 * 40];
  __shared__ __align__(16) u16 Bls[2][128 * 40];
  int t = threadIdx.x, wv = t >> 6, lane = t & 63;
  int wm = (wv >> 1) * 64, wn = (wv & 1) * 64, fr = lane & 15, ko = lane >> 4;

  auto loadA = [&](int cc, int s) -> u16x16 {
    int r = s >> 7, rest = s & 127, w = rest >> 1, half = rest & 1;
    int hs = hp * 2 - 1 + r;
    u16x16 v = {};
    if ((unsigned)hs < 64u)
      v = *(const u16x16*)(v3b + (((size_t)b * 64 + hs) * 64 + w) * 256 + cc * 32 + half * 16);
    return v;
  };
  auto storeA = [&](int s, u16x16 v) {
    int r = s >> 7, rest = s & 127, w = rest >> 1, half = rest & 1;
    *(u16x16*)(Ain + (r * 64 + w) * 40 + half * 16) = v;
  };
  auto loadB = [&](int tap, int cc) -> u16x16 {
    int n = t >> 1, half = t & 1;
    return *(const u16x16*)(Wt + ((size_t)tap * 256 + oh * 128 + n) * 256 + cc * 32 + half * 16);
  };
  auto storeB = [&](int bsel, u16x16 v) {
    int n = t >> 1, half = t & 1;
    *(u16x16*)(Bls[bsel] + n * 40 + half * 16) = v;
  };

  u16x16 pA0 = loadA(0, t), pA1 = loadA(0, t + 256);
  u16x16 rB = loadB(0, 0);
  storeA(t, pA0); storeA(t + 256, pA1); storeB(0, rB);
  rB = loadB(1, 0);
  __syncthreads();

  f32x4 acc[4][4] = {};
  int buf = 0;
  for (int cc = 0; cc < 8; ++cc) {
#pragma unroll
    for (int tap = 0; tap < 9; ++tap) {
      const int dh = tap / 3 - 1, dw = tap % 3 - 1;
      s16x8 af[4], bfr[4];
#pragma unroll
      for (int i = 0; i < 4; ++i) {
        int m = wm + i * 16 + fr, r = m >> 6, wq = m & 63;
        int wqd = wq + dw;
        s16x8 v = {};
        if ((unsigned)wqd < 64u)
          v = *(const s16x8*)(Ain + ((r + dh + 1) * 64 + wqd) * 40 + ko * 8);
        af[i] = v;
      }
#pragma unroll
      for (int j = 0; j < 4; ++j)
        bfr[j] = *(const s16x8*)(Bls[buf] + (wn + j * 16 + fr) * 40 + ko * 8);
#pragma unroll
      for (int i = 0; i < 4; ++i)
#pragma unroll
        for (int j = 0; j < 4; ++j)
          acc[i][j] = __builtin_amdgcn_mfma_f32_16x16x32_bf16(af[i], bfr[j], acc[i][j], 0, 0, 0);
      const int u = cc * 9 + tap;
      if (u < 71) {
        if (tap == 8) {
          __syncthreads();  // Ain readers done before rewrite
          storeA(t, pA0); storeA(t + 256, pA1);
        }
        storeB(buf ^ 1, rB);
        if (u + 2 <= 71) {
          const int un = u + 2;
          rB = loadB(un % 9, un / 9);
        }
        if (tap == 7 && cc < 7) { pA0 = loadA(cc + 1, t); pA1 = loadA(cc + 1, t + 256); }
        __syncthreads();
        buf ^= 1;
      }
    }
  }
#pragma unroll
  for (int i = 0; i < 4; ++i) {
    int m0 = wm + i * 16 + ko * 4;
#pragma unroll
    for (int j = 0; j < 4; ++j) {
      int och = oh * 128 + wn + j * 16 + fr;
      float bv = bias[och];
#pragma unroll
      for (int r = 0; r < 4; ++r) {
        float v = fmaxf(acc[i][j][r] + bv, 0.f);
        pre[((size_t)b * 4096 + hp * 128 + m0 + r) * 256 + och] = f2bf(v);
      }
    }
  }
}

// ---------------- fused red -> v,k (norm) + local gram partial per 128-token tile ----------------
__global__ __launch_bounds__(256) void k_qkv(
    const u16* __restrict__ in,    // [B*4096][256]
    const u16* __restrict__ redW,  // [128][256]
    const u16* __restrict__ wkW,   // [128][128]
    const u16* __restrict__ wvW,   // [128][128]
    const float* __restrict__ kb, const float* __restrict__ vb,
    u16* __restrict__ vout,        // [B*4096][128]
    float* __restrict__ gp) {      // [B*32][128][128]
  int nt = blockIdx.x, b = blockIdx.y;
  const u16* Ab = in + ((size_t)b * 4096 + nt * 128) * 256;
  __shared__ __align__(16) u16 Ald[128 * 40];
  __shared__ __align__(16) u16 Bld[128 * 40];
  __shared__ __align__(16) u16 T[128 * 136];
  __shared__ float SS[2][128];
  int t = threadIdx.x, wv = t >> 6, lane = t & 63;
  int wm = (wv >> 1) * 64, wn = (wv & 1) * 64, fr = lane & 15, ko = lane >> 4;
  f32x4 acc[4][4] = {};
  for (int kc = 0; kc < 256; kc += 32) {
    for (int s = t; s < 512; s += 256) {
      int r = s >> 2, ks = s & 3;
      *(u16x8*)(Ald + r * 40 + ks * 8) = *(const u16x8*)(Ab + (size_t)r * 256 + kc + ks * 8);
    }
    for (int s = t; s < 512; s += 256) {
      int r = s >> 2, ks = s & 3;
      *(u16x8*)(Bld + r * 40 + ks * 8) = *(const u16x8*)(redW + (size_t)r * 256 + kc + ks * 8);
    }
    __syncthreads();
    s16x8 af[4], bf[4];
#pragma unroll
    for (int i = 0; i < 4; ++i) af[i] = *(const s16x8*)(Ald + (wm + i * 16 + fr) * 40 + ko * 8);
#pragma unroll
    for (int j = 0; j < 4; ++j) bf[j] = *(const s16x8*)(Bld + (wn + j * 16 + fr) * 40 + ko * 8);
#pragma unroll
    for (int i = 0; i < 4; ++i)
#pragma unroll
      for (int j = 0; j < 4; ++j)
        acc[i][j] = __builtin_amdgcn_mfma_f32_16x16x32_bf16(af[i], bf[j], acc[i][j], 0, 0, 0);
    __syncthreads();
  }
#pragma unroll
  for (int i = 0; i < 4; ++i)
#pragma unroll
    for (int j = 0; j < 4; ++j)
#pragma unroll
      for (int r = 0; r < 4; ++r)
        T[(wm + i * 16 + ko * 4 + r) * 136 + wn + j * 16 + fr] = f2bf(acc[i][j][r]);

  for (int z = 0; z < 2; ++z) {
    const u16* W = z ? wkW : wvW;
    const float* bias = z ? kb : vb;
    f32x4 a2[4][4] = {};
#pragma unroll
    for (int h = 0; h < 2; ++h) {
      __syncthreads();
      for (int s = t; s < 512; s += 256) {
        int r = s >> 2, ks = s & 3;
        *(u16x8*)(Ald + r * 40 + ks * 8) = *(const u16x8*)(W + (size_t)r * 128 + h * 64 + ks * 8);
      }
      for (int s = t; s < 512; s += 256) {
        int r = s >> 2, ks = s & 3;
        *(u16x8*)(Bld + r * 40 + ks * 8) = *(const u16x8*)(W + (size_t)r * 128 + h * 64 + 32 + ks * 8);
      }
      __syncthreads();
#pragma unroll
      for (int kk = 0; kk < 2; ++kk) {
        const u16* Bsrc = kk ? Bld : Ald;
        s16x8 af[4], bf[4];
#pragma unroll
        for (int i = 0; i < 4; ++i)
          af[i] = *(const s16x8*)(T + (size_t)(wm + i * 16 + fr) * 136 + h * 64 + kk * 32 + ko * 8);
#pragma unroll
        for (int j = 0; j < 4; ++j)
          bf[j] = *(const s16x8*)(Bsrc + (wn + j * 16 + fr) * 40 + ko * 8);
#pragma unroll
        for (int i = 0; i < 4; ++i)
#pragma unroll
          for (int j = 0; j < 4; ++j)
            a2[i][j] = __builtin_amdgcn_mfma_f32_16x16x32_bf16(af[i], bf[j], a2[i][j], 0, 0, 0);
      }
    }
    float bj[4];
#pragma unroll
    for (int j = 0; j < 4; ++j) bj[j] = bias[wn + j * 16 + fr];
    float pss[4][4];
#pragma unroll
    for (int i = 0; i < 4; ++i)
#pragma unroll
      for (int r = 0; r < 4; ++r) pss[i][r] = 0.f;
#pragma unroll
    for (int i = 0; i < 4; ++i)
#pragma unroll
      for (int j = 0; j < 4; ++j)
#pragma unroll
        for (int r = 0; r < 4; ++r) {
          float v = a2[i][j][r] + bj[j];
          a2[i][j][r] = v;
          pss[i][r] += v * v;
        }
#pragma unroll
    for (int m = 1; m < 16; m <<= 1)
#pragma unroll
      for (int i = 0; i < 4; ++i)
#pragma unroll
        for (int r = 0; r < 4; ++r) pss[i][r] += __shfl_xor(pss[i][r], m);
    if (fr == 0)
#pragma unroll
      for (int i = 0; i < 4; ++i)
#pragma unroll
        for (int r = 0; r < 4; ++r) SS[wv & 1][wm + i * 16 + ko * 4 + r] = pss[i][r];
    __syncthreads();
    float sc[4][4];
#pragma unroll
    for (int i = 0; i < 4; ++i)
#pragma unroll
      for (int r = 0; r < 4; ++r) {
        int tok = wm + i * 16 + ko * 4 + r;
        float s2 = SS[0][tok] + SS[1][tok];
        sc[i][r] = 1.f / fmaxf(sqrtf(s2), 1e-12f);
      }
#pragma unroll
    for (int i = 0; i < 4; ++i)
#pragma unroll
      for (int j = 0; j < 4; ++j)
#pragma unroll
        for (int r = 0; r < 4; ++r) a2[i][j][r] *= sc[i][r];
    if (z == 0) {
      size_t tokbase = (size_t)b * 4096 + nt * 128;
#pragma unroll
      for (int i = 0; i < 4; ++i)
#pragma unroll
        for (int j = 0; j < 4; ++j) {
          u16* dst = vout + (tokbase + wm + i * 16 + ko * 4) * 128 + wn + j * 16 + fr;
#pragma unroll
          for (int r = 0; r < 4; ++r) dst[(size_t)r * 128] = f2bf(a2[i][j][r]);
        }
    } else {
#pragma unroll
      for (int i = 0; i < 4; ++i)
#pragma unroll
        for (int j = 0; j < 4; ++j)
#pragma unroll
          for (int r = 0; r < 4; ++r)
            T[(size_t)(wn + j * 16 + fr) * 136 + wm + i * 16 + ko * 4 + r] = f2bf(a2[i][j][r]);
      __syncthreads();
      f32x4 g3[4][4] = {};
      for (int kc = 0; kc < 128; kc += 32) {
        s16x8 af[4], bf[4];
#pragma unroll
        for (int i = 0; i < 4; ++i)
          af[i] = *(const s16x8*)(T + (size_t)(wm + i * 16 + fr) * 136 + kc + ko * 8);
#pragma unroll
        for (int j = 0; j < 4; ++j)
          bf[j] = *(const s16x8*)(T + (size_t)(wn + j * 16 + fr) * 136 + kc + ko * 8);
#pragma unroll
        for (int i = 0; i < 4; ++i)
#pragma unroll
          for (int j = 0; j < 4; ++j)
            g3[i][j] = __builtin_amdgcn_mfma_f32_16x16x32_bf16(af[i], bf[j], g3[i][j], 0, 0, 0);
      }
      float* dst = gp + ((size_t)(b * 32 + nt)) * 16384;
#pragma unroll
      for (int i = 0; i < 4; ++i) {
        int m0 = wm + i * 16 + ko * 4;
#pragma unroll
        for (int j = 0; j < 4; ++j) {
          int nc = wn + j * 16 + fr;
#pragma unroll
          for (int r = 0; r < 4; ++r) dst[(size_t)(m0 + r) * 128 + nc] = g3[i][j][r];
        }
      }
    }
  }
}

// ---------------- fused PV + rise per 128-token tile ----------------
template <int MODE>
__global__ __launch_bounds__(256) void k_pvrise(
    const u16* __restrict__ vbuf,   // [B*4096][128]
    const u16* __restrict__ attnb,  // [B][128][128]
    const u16* __restrict__ riseW,  // [256][128]
    const float* __restrict__ bias,
    const u16* __restrict__ add0, const u16* __restrict__ add1,
    u16* __restrict__ out0, u16* __restrict__ out1, float* __restrict__ outf) {
  int nt = blockIdx.x, b = blockIdx.y;
  const u16* Ab = vbuf + ((size_t)b * 4096 + nt * 128) * 128;
  const u16* Bb = attnb + (size_t)b * 128 * 128;
  __shared__ __align__(16) u16 Ald[128 * 40];
  __shared__ __align__(16) u16 Bld[128 * 40];
  __shared__ __align__(16) u16 T[128 * 136];
  int t = threadIdx.x, wv = t >> 6, lane = t & 63;
  int wm = (wv >> 1) * 64, wn = (wv & 1) * 64, fr = lane & 15, ko = lane >> 4;
  f32x4 acc[4][4] = {};
  for (int kc = 0; kc < 128; kc += 32) {
    for (int s = t; s < 512; s += 256) {
      int r = s >> 2, ks = s & 3;
      *(u16x8*)(Ald + r * 40 + ks * 8) = *(const u16x8*)(Ab + (size_t)r * 128 + kc + ks * 8);
    }
    for (int s = t; s < 512; s += 256) {
      int r = s >> 2, ks = s & 3;
      *(u16x8*)(Bld + r * 40 + ks * 8) = *(const u16x8*)(Bb + (size_t)r * 128 + kc + ks * 8);
    }
    __syncthreads();
    s16x8 af[4], bf[4];
#pragma unroll
    for (int i = 0; i < 4; ++i) af[i] = *(const s16x8*)(Ald + (wm + i * 16 + fr) * 40 + ko * 8);
#pragma unroll
    for (int j = 0; j < 4; ++j) bf[j] = *(const s16x8*)(Bld + (wn + j * 16 + fr) * 40 + ko * 8);
#pragma unroll
    for (int i = 0; i < 4; ++i)
#pragma unroll
      for (int j = 0; j < 4; ++j)
        acc[i][j] = __builtin_amdgcn_mfma_f32_16x16x32_bf16(af[i], bf[j], acc[i][j], 0, 0, 0);
    __syncthreads();
  }
#pragma unroll
  for (int i = 0; i < 4; ++i)
#pragma unroll
    for (int j = 0; j < 4; ++j)
#pragma unroll
      for (int r = 0; r < 4; ++r)
        T[(wm + i * 16 + ko * 4 + r) * 136 + wn + j * 16 + fr] = f2bf(acc[i][j][r]);

  size_t tokbase = (size_t)b * 4096 + nt * 128;
  for (int z = 0; z < 2; ++z) {
    const u16* W = riseW + (size_t)z * 128 * 128;
    f32x4 a2[4][4] = {};
#pragma unroll
    for (int h = 0; h < 2; ++h) {
      __syncthreads();
      for (int s = t; s < 512; s += 256) {
        int r = s >> 2, ks = s & 3;
        *(u16x8*)(Ald + r * 40 + ks * 8) = *(const u16x8*)(W + (size_t)r * 128 + h * 64 + ks * 8);
      }
      for (int s = t; s < 512; s += 256) {
        int r = s >> 2, ks = s & 3;
        *(u16x8*)(Bld + r * 40 + ks * 8) = *(const u16x8*)(W + (size_t)r * 128 + h * 64 + 32 + ks * 8);
      }
      __syncthreads();
#pragma unroll
      for (int kk = 0; kk < 2; ++kk) {
        const u16* Bsrc = kk ? Bld : Ald;
        s16x8 af[4], bf[4];
#pragma unroll
        for (int i = 0; i < 4; ++i)
          af[i] = *(const s16x8*)(T + (size_t)(wm + i * 16 + fr) * 136 + h * 64 + kk * 32 + ko * 8);
#pragma unroll
        for (int j = 0; j < 4; ++j)
          bf[j] = *(const s16x8*)(Bsrc + (wn + j * 16 + fr) * 40 + ko * 8);
#pragma unroll
        for (int i = 0; i < 4; ++i)
#pragma unroll
          for (int j = 0; j < 4; ++j)
            a2[i][j] = __builtin_amdgcn_mfma_f32_16x16x32_bf16(af[i], bf[j], a2[i][j], 0, 0, 0);
      }
    }
#pragma unroll
    for (int i = 0; i < 4; ++i) {
      int m0 = wm + i * 16 + ko * 4;
#pragma unroll
      for (int j = 0; j < 4; ++j) {
        int o = z * 128 + wn + j * 16 + fr;
        float bv = bias[o];
        size_t idx = (tokbase + m0) * 256 + o;
        if constexpr (MODE == 3) {
#pragma unroll
          for (int r = 0; r < 4; ++r) {
            float f1v = a2[i][j][r] + bv;
            out0[idx + (size_t)r * 256] = f2bf(f1v);
            out1[idx + (size_t)r * 256] = f2bf(f1v + bf2f(add0[idx + (size_t)r * 256]));
          }
        } else {
          f32x4 vv;
#pragma unroll
          for (int r = 0; r < 4; ++r)
            vv[r] = a2[i][j][r] + bv + bf2f(add0[idx + (size_t)r * 256]) +
                    bf2f(add1[idx + (size_t)r * 256]);
          *(f32x4*)(outf + ((size_t)b * 256 + o) * 4096 + nt * 128 + m0) = vv;
        }
      }
    }
  }
}

// ---------------- softmax over j of 30*G (32 partials) ----------------
__global__ void k_soft(const float* __restrict__ gp, u16* __restrict__ attn) {
  int i = blockIdx.x, b = blockIdx.y, l = threadIdx.x;
  float s0 = 0.f, s1 = 0.f;
  for (int ks = 0; ks < 32; ++ks) {
    const float* row = gp + ((size_t)(b * 32 + ks)) * 16384 + (size_t)i * 128;
    s0 += row[l]; s1 += row[l + 64];
  }
  s0 *= 30.f; s1 *= 30.f;
  float m = fmaxf(s0, s1);
  for (int o = 32; o; o >>= 1) m = fmaxf(m, __shfl_xor(m, o));
  float e0 = expf(s0 - m), e1 = expf(s1 - m);
  float s = e0 + e1;
  for (int o = 32; o; o >>= 1) s += __shfl_xor(s, o);
  float inv = 1.f / s;
  u16* dst = attn + ((size_t)b * 128 + i) * 128;
  dst[l] = f2bf(e0 * inv);
  dst[l + 64] = f2bf(e1 * inv);
}

extern "C" void kernel_launch(void* const* d_in, const int* in_sizes, int n_in,
                              void* d_out, int out_size, void* d_ws, size_t ws_size,
                              hipStream_t stream) {
  (void)in_sizes; (void)n_in; (void)out_size; (void)ws_size;
  const float* x0 = (const float*)d_in[0];
  const float* x1 = (const float*)d_in[1];
  const float* x2 = (const float*)d_in[2];
  const float* x3 = (const float*)d_in[3];
  const float* x4 = (const float*)d_in[4];
  const float* spec_w1 = (const float*)d_in[5];
  const float* spec_w2 = (const float*)d_in[6];
  const float* comm_w1 = (const float*)d_in[7];
  const float* comm_w2 = (const float*)d_in[8];
  const float* pre_w = (const float*)d_in[9];
  const float* pre_bias = (const float*)d_in[10];
  const float* wk1_w = (const float*)d_in[11];
  const float* wk1_b = (const float*)d_in[12];
  const float* wv1_w = (const float*)d_in[13];
  const float* wv1_b = (const float*)d_in[14];
  const float* red1_w = (const float*)d_in[15];
  const float* rise1_w = (const float*)d_in[16];
  const float* rise1_b = (const float*)d_in[17];
  const float* wk2_w = (const float*)d_in[18];
  const float* wk2_b = (const float*)d_in[19];
  const float* wv2_w = (const float*)d_in[20];
  const float* wv2_b = (const float*)d_in[21];
  const float* red2_w = (const float*)d_in[22];
  const float* rise2_w = (const float*)d_in[23];
  const float* rise2_b = (const float*)d_in[24];
  float* out = (float*)d_out;

  char* wsp = (char*)d_ws;
  size_t off = 0;
  auto alloc = [&](size_t bytes) -> void* {
    off = (off + 255) & ~(size_t)255;
    void* p = wsp + off;
    off += bytes;
    return p;
  };
  float* pd = (float*)alloc(16 * 256 * 4);
  float* ps = (float*)alloc(16 * 256 * 4);
  float* h1b = (float*)alloc(2 * 16 * 320 * 4);
  float* h2b = (float*)alloc(2 * 16 * 1280 * 4);
  u16* v3b = (u16*)alloc((size_t)16 * 4096 * 256 * 2);
  u16* Wtc = (u16*)alloc((size_t)9 * 256 * 256 * 2);
  u16* wall = (u16*)alloc((size_t)196608 * 2);  // 8 small weights, contiguous
  u16* red1b = wall;
  u16* wk1b = wall + 32768;
  u16* wv1b = wall + 49152;
  u16* rise1b = wall + 65536;
  u16* red2b = wall + 98304;
  u16* wk2b = wall + 131072;
  u16* wv2b = wall + 147456;
  u16* rise2b = wall + 163840;
  u16* pre = (u16*)alloc((size_t)16 * 4096 * 256 * 2);   // reused as in2 = f1+v3
  float* gpart = (float*)alloc((size_t)16 * 32 * 128 * 128 * 4);  // 32 MB
  u16* vbuf = (u16*)alloc((size_t)16 * 4096 * 128 * 2);
  u16* attn = (u16*)alloc((size_t)16 * 128 * 128 * 2);
  u16* spacer = (u16*)alloc((size_t)16 * 4096 * 128 * 2);  // keeps hx arena span
  u16* f1b = (u16*)alloc((size_t)16 * 4096 * 256 * 2);
  (void)spacer;
  u16* in2b = pre;
  // fp16 x1..x4 arena ALIASES the post-v3 buffers (pre..f1b span >= 134.2 MB).
  // Safe: written by k_pool, read by k_v3, both BEFORE k_conv first writes `pre`.
  f16* hx = (f16*)pre;
  const size_t HXN = (size_t)16 * 256 * 4096;  // elems per tensor
  f16* hx1 = hx;
  f16* hx2 = hx + HXN;
  f16* hx3 = hx + 2 * HXN;
  f16* hx4 = hx + 3 * HXN;

  // weight prep (one launch)
  k_prep<<<dim3(3072), 256, 0, stream>>>(wall, red1_w, wk1_w, wv1_w, rise1_w,
                                         red2_w, wk2_w, wv2_w, rise2_w, Wtc, pre_w);

  k_pool<<<dim3(256, 16), 256, 0, stream>>>(x0, x1, x2, x3, x4, pd, ps, hx1, hx2, hx3, hx4);
  k_se1<<<dim3(80, 16, 2), 256, 0, stream>>>(pd, ps, spec_w1, comm_w1, h1b);
  k_se2<<<dim3(320, 16, 2), 256, 0, stream>>>(h1b, spec_w2, comm_w2, h2b);
  k_v3<<<dim3(64, 16), 256, 0, stream>>>(x0, hx1, hx2, hx3, hx4, h2b, v3b);
  k_conv<<<dim3(1024), 256, 0, stream>>>(v3b, Wtc, pre_bias, pre);

  // ---- tdec 1 ----
  k_qkv<<<dim3(32, 16), 256, 0, stream>>>(pre, red1b, wk1b, wv1b, wk1_b, wv1_b, vbuf, gpart);
  k_soft<<<dim3(128, 16), 64, 0, stream>>>(gpart, attn);
  k_pvrise<3><<<dim3(32, 16), 256, 0, stream>>>(vbuf, attn, rise1b, rise1_b,
      v3b, nullptr, f1b, in2b, nullptr);

  // ---- tdec 2 (input in2b aliases pre) ----
  k_qkv<<<dim3(32, 16), 256, 0, stream>>>(in2b, red2b, wk2b, wv2b, wk2_b, wv2_b, vbuf, gpart);
  k_soft<<<dim3(128, 16), 64, 0, stream>>>(gpart, attn);
  k_pvrise<4><<<dim3(32, 16), 256, 0, stream>>>(vbuf, attn, rise2b, rise2_b,
      f1b, v3b, nullptr, nullptr, out);
}